// Round 1
// baseline (400.902 us; speedup 1.0000x reference)
//
#include <hip/hip_runtime.h>

#define NB    32768      // labels per batch
#define NC    1000       // classes
#define ND    1024       // feature dim
#define ND4   256        // float4 per row
#define MOM   0.9f

// ws layout (int words):
//   [0,    1000) counts
//   [1024, 2024) cursors
//   [2048, 2050) loss accum (float: sum, n_present)
//   [3072, 4096) offsets (exclusive scan, padded to 1024)
//   [4096, 4096+32768) sorted row indices
// zeroed region: first 2050 words (counts+cursors+loss)

__global__ void hist_k(const int* __restrict__ l, int* __restrict__ counts) {
    int i = blockIdx.x * blockDim.x + threadIdx.x;
    if (i < NB) atomicAdd(&counts[l[i]], 1);
}

__global__ void scan_k(const int* __restrict__ counts, int* __restrict__ offsets) {
    __shared__ int s[1024];
    int t = threadIdx.x;
    int v = (t < NC) ? counts[t] : 0;
    s[t] = v;
    __syncthreads();
    for (int o = 1; o < 1024; o <<= 1) {
        int a = (t >= o) ? s[t - o] : 0;
        __syncthreads();
        s[t] += a;
        __syncthreads();
    }
    offsets[t] = s[t] - v;   // exclusive scan
}

__global__ void scatter_k(const int* __restrict__ l, const int* __restrict__ offsets,
                          int* __restrict__ cursors, int* __restrict__ sorted) {
    int i = blockIdx.x * blockDim.x + threadIdx.x;
    if (i < NB) {
        int c = l[i];
        int pos = offsets[c] + atomicAdd(&cursors[c], 1);
        sorted[pos] = i;
    }
}

__device__ __forceinline__ float block_sum(float v, float* sm, int t) {
    __syncthreads();                       // protect sm reuse across calls
    #pragma unroll
    for (int o = 32; o > 0; o >>= 1) v += __shfl_down(v, o, 64);
    if ((t & 63) == 0) sm[t >> 6] = v;
    __syncthreads();
    if (t == 0) sm[0] = sm[0] + sm[1] + sm[2] + sm[3];
    __syncthreads();
    return sm[0];
}

// one block per class: gather rows, mean, EMA, normalize, align loss
__global__ __launch_bounds__(256) void class_k(
        const float4* __restrict__ x4,
        const float4* __restrict__ ci4,
        const float4* __restrict__ cs4,
        const int* __restrict__ counts,
        const int* __restrict__ offsets,
        const int* __restrict__ sorted,
        float* __restrict__ loss_acc) {
    int c = blockIdx.x;
    int t = threadIdx.x;
    int cnt = counts[c];
    int off = offsets[c];

    float4 acc = make_float4(0.f, 0.f, 0.f, 0.f);
    int j = 0;
    for (; j + 2 <= cnt; j += 2) {
        int i0 = sorted[off + j];
        int i1 = sorted[off + j + 1];
        float4 a0 = x4[(long)i0 * ND4 + t];
        float4 b0 = x4[((long)i0 + NB) * ND4 + t];
        float4 a1 = x4[(long)i1 * ND4 + t];
        float4 b1 = x4[((long)i1 + NB) * ND4 + t];
        acc.x += (a0.x + b0.x) + (a1.x + b1.x);
        acc.y += (a0.y + b0.y) + (a1.y + b1.y);
        acc.z += (a0.z + b0.z) + (a1.z + b1.z);
        acc.w += (a0.w + b0.w) + (a1.w + b1.w);
    }
    if (j < cnt) {
        int i0 = sorted[off + j];
        float4 a0 = x4[(long)i0 * ND4 + t];
        float4 b0 = x4[((long)i0 + NB) * ND4 + t];
        acc.x += a0.x + b0.x;
        acc.y += a0.y + b0.y;
        acc.z += a0.z + b0.z;
        acc.w += a0.w + b0.w;
    }

    float inv = 1.0f / fmaxf((float)cnt, 1.0f);
    float4 ci = ci4[c * ND4 + t];
    float4 upd;
    upd.x = ci.x * MOM + (acc.x * inv) * (1.0f - MOM);
    upd.y = ci.y * MOM + (acc.y * inv) * (1.0f - MOM);
    upd.z = ci.z * MOM + (acc.z * inv) * (1.0f - MOM);
    upd.w = ci.w * MOM + (acc.w * inv) * (1.0f - MOM);

    __shared__ float sm[4];
    float n2 = block_sum(upd.x * upd.x + upd.y * upd.y + upd.z * upd.z + upd.w * upd.w,
                         sm, t);
    float rn = 1.0f / sqrtf(n2);

    float4 nw;
    if (cnt > 0) {
        nw.x = upd.x * rn; nw.y = upd.y * rn; nw.z = upd.z * rn; nw.w = upd.w * rn;
    } else {
        nw = ci;
    }

    float4 cs = cs4[c * ND4 + t];
    float dx = nw.x - cs.x, dy = nw.y - cs.y, dz = nw.z - cs.z, dw = nw.w - cs.w;
    float lp = block_sum(dx * dx + dy * dy + dz * dz + dw * dw, sm, t);

    if (t == 0 && cnt > 0) {
        atomicAdd(&loss_acc[0], lp);
        atomicAdd(&loss_acc[1], 1.0f);
    }
}

__global__ void final_k(const float* __restrict__ loss_acc, float* __restrict__ out) {
    out[0] = loss_acc[0] / fmaxf(loss_acc[1], 1.0f);
}

extern "C" void kernel_launch(void* const* d_in, const int* in_sizes, int n_in,
                              void* d_out, int out_size, void* d_ws, size_t ws_size,
                              hipStream_t stream) {
    const float* x  = (const float*)d_in[0];
    const float* ci = (const float*)d_in[1];
    const float* cs = (const float*)d_in[2];
    const int*   l  = (const int*)d_in[3];
    float* out = (float*)d_out;

    int* ws      = (int*)d_ws;
    int* counts  = ws;
    int* cursors = ws + 1024;
    float* loss  = (float*)(ws + 2048);
    int* offsets = ws + 3072;
    int* sorted  = ws + 4096;

    // zero counts/cursors/loss (first 2050 words)
    hipMemsetAsync(d_ws, 0, 2050 * sizeof(int), stream);

    hist_k<<<NB / 256, 256, 0, stream>>>(l, counts);
    scan_k<<<1, 1024, 0, stream>>>(counts, offsets);
    scatter_k<<<NB / 256, 256, 0, stream>>>(l, offsets, cursors, sorted);
    class_k<<<NC, 256, 0, stream>>>((const float4*)x, (const float4*)ci,
                                    (const float4*)cs, counts, offsets, sorted, loss);
    final_k<<<1, 1, 0, stream>>>(loss, out);
}